// Round 1
// baseline (659.777 us; speedup 1.0000x reference)
//
#include <hip/hip_runtime.h>
#include <math.h>

// NetNew_17162689315115: 8-layer EQL-style net, B=524288 rows.
// Reference is numpy float64; chaotic map (sin/cos at |z|~1e8-1e14) -> ENTIRE
// chain in fp64, bitwise-frozen since R3 (absmax 1245184 / thr 1646264).
// DO NOT reassociate: each z[j] = fma(W[j,k], h[k], acc) ascending k.
//
// Evidence log:
//  R4 407us (fp64 weights pre-widened to d_ws). R5/R6 allocator hints:
//  regress badly — do not reintroduce. R7 block 64 vs 256: neutral.
//  R8 j-blocking: exactly neutral -> "spills" are AGPR moves (unified file:
//  ~112 arch VGPR + ~112 AGPR = 224 total -> 2 waves/SIMD hard cap; explains
//  occupancy 22.5% at all VGPR counts and zero scratch HBM traffic).
//  R9 I$ shrink (rolled j-loop + shared noinline transcendentals):
//  407 -> 222us, busy-time 265 -> 127us. I$ thrash confirmed.
//  R10 merged 4 transcendentals into one call: ~neutral — ocml sin/cos are
//  branchy (PH slow path), scheduler can't interleave across control flow.
//  R11 inline exp/log, shared noinline sincos: 222 -> 214us (VALUBusy 56%,
//  occupancy 22.7% == 2 waves/SIMD, HBM 0.6% — latency-bound on wave count).
// R12: break the 224-reg occupancy cap. Move the NEWEST 26 h entries
// (h[0..26) = layer-8/7 outputs + 8 of layer-6) to LDS — these have the
// FEWEST readers (1-3 each vs 7 for the oldest tail), so LDS traffic stays
// ~O(100) ds ops/thread. Saves 52 regs; __launch_bounds__(64,3) forces the
// allocator to 168 total -> 3 waves/SIMD. LDS 26*8*64 = 13312 B/WG -> 12
// WGs/CU = 159.75/160 KiB. Bitwise-neutral: every h value computed by the
// identical op sequence; only its storage location changes.

static constexpr double MAX_MLT   = 99999999.0;
static constexpr double MAX_DIV   = 9999.0;
static constexpr double MAX_EXP_C = 17.0;
static constexpr double MIN_DENOM = 0.0001;

static constexpr int IN0   = 8;   // vari_num + const_num
static constexpr int VDIM  = 13;  // rows of each W
static constexpr int NOPS  = 9;   // ops appended per layer
static constexpr int FDIM  = 80;  // final h dim: 8 + 8*9
static constexpr int SPLIT = 26;  // h[0..SPLIT) lives in LDS, rest in regs
static constexpr int BDIM  = 64;  // one wave per workgroup

// layer weight element counts and fp64 workspace offsets
// in_dims: 8,17,26,35,44,53,62,71 ; W_i is 13 x in_dim ; Wf is 1 x 80
static constexpr int WSZ[9]  = {104, 221, 338, 455, 572, 689, 806, 923, 80};
static constexpr int WOFF[9] = {0, 104, 325, 663, 1118, 1690, 2379, 3185, 4108};

// ---- prep: widen fp32 weights -> fp64 workspace (exact, bitwise-neutral) ----
__global__ void widen_kernel(const float* __restrict__ s0, const float* __restrict__ s1,
                             const float* __restrict__ s2, const float* __restrict__ s3,
                             const float* __restrict__ s4, const float* __restrict__ s5,
                             const float* __restrict__ s6, const float* __restrict__ s7,
                             const float* __restrict__ s8, double* __restrict__ dst) {
    int seg = blockIdx.y;
    int i   = blockIdx.x * blockDim.x + threadIdx.x;
    const float* src;
    switch (seg) {
        case 0: src = s0; break; case 1: src = s1; break; case 2: src = s2; break;
        case 3: src = s3; break; case 4: src = s4; break; case 5: src = s5; break;
        case 6: src = s6; break; case 7: src = s7; break; default: src = s8; break;
    }
    if (i < WSZ[seg]) dst[WOFF[seg] + i] = (double)src[i];
}

// ---- one shared body for the two PH-heavy (branchy) functions ----
struct D2 { double s, c; };
__device__ __attribute__((noinline))
D2 d_sincos2(double as, double ac) {
    D2 r;
    r.s = sin(as);
    r.c = cos(ac);
    return r;
}

// _clip_mag forward, float64: scale = |mx/v|, o = where(|v|>=mx, v*scale, v).
// NaN passes through (compare false), matching jnp.where.
__device__ __forceinline__ double clip_ref(double v, double mx) {
    double scale = fabs(mx / v);
    double vs    = v * scale;
    return (fabs(v) >= mx) ? vs : v;
}

// Split-h accessors. All call sites have compile-time-foldable k (fully
// unrolled k-loops / constexpr BO), so the branch folds and the reg-half
// indices stay static (register-resident). LDS layout [k][tid]: lane-
// contiguous 8B -> canonical conflict-free b64 pattern.
__device__ __forceinline__ double h_rd(const double (&h)[FDIM],
                                       const double (*hl)[BDIM], int tid, int k) {
    if (k < SPLIT) return hl[k < SPLIT ? k : 0][tid];
    return h[k];
}
__device__ __forceinline__ void h_wr(double (&h)[FDIM], double (*hl)[BDIM],
                                     int tid, int k, double v) {
    if (k < SPLIT) hl[k < SPLIT ? k : 0][tid] = v;
    else           h[k] = v;
}

template<int IN_DIM, int BASE>
__device__ __forceinline__ void layer_step(const double* __restrict__ W,
                                           double (&h)[FDIM],
                                           double (*hl)[BDIM], int tid) {
    double z[VDIM];
    // Rolled j-loop (unroll 2): each z[j] is the same ascending-k fma chain
    // as the fully-unrolled form -> bitwise equal. k stays unrolled so every
    // h index is compile-time constant (register/LDS-resident, no scratch).
    #pragma unroll 2
    for (int j = 0; j < VDIM; ++j) {
        const double* Wr = W + j * IN_DIM;
        double acc = 0.0;
        #pragma unroll
        for (int k = 0; k < IN_DIM; ++k) {
            acc = fma(Wr[k], h_rd(h, hl, tid, BASE + k), acc);  // frozen order
        }
        z[j] = acc;
    }
    constexpr int BO = BASE - NOPS;
    // op order: + - * / sin cos exp log square, consuming z cols in order
    h_wr(h, hl, tid, BO + 0, z[0] + z[1]);
    h_wr(h, hl, tid, BO + 1, z[2] - z[3]);
    h_wr(h, hl, tid, BO + 2, clip_ref(z[4] * z[5], MAX_MLT));
    {
        double b     = z[7];
        double denom = (b == 0.0) ? (b + MIN_DENOM) : b;
        h_wr(h, hl, tid, BO + 3, clip_ref(z[6] / denom, MAX_DIV));
    }
    {
        D2 t = d_sincos2(z[8], z[9]);   // shared noinline: PH-heavy bodies
        h_wr(h, hl, tid, BO + 4, t.s);
        h_wr(h, hl, tid, BO + 5, t.c);
    }
    {
        double a    = z[10];
        double safe = (a >= MAX_EXP_C) ? (a * (MAX_EXP_C / a)) : a;
        h_wr(h, hl, tid, BO + 6, exp(safe));  // inlined: branch-light
    }
    h_wr(h, hl, tid, BO + 7, log(fabs(z[11])));  // inlined: branch-light
    h_wr(h, hl, tid, BO + 8, clip_ref(z[12] * z[12], MAX_MLT));
}

__global__ void __launch_bounds__(BDIM, 3)
net_kernel(const float* __restrict__ x, const double* __restrict__ Wd,
           float* __restrict__ out, int nrows) {
    __shared__ double hl[SPLIT][BDIM];  // h[0..26): 13312 B -> 12 WGs/CU
    int tid = threadIdx.x;
    int row = blockIdx.x * blockDim.x + tid;
    if (row >= nrows) return;

    double h[FDIM];  // only [SPLIT..FDIM) actually used -> 54 doubles in regs

    // x occupies the TAIL of the final feature vector (each layer prepends).
    const float4* x4 = reinterpret_cast<const float4*>(x);
    float4 xa = x4[row * 2 + 0];
    float4 xb = x4[row * 2 + 1];
    h[72] = (double)xa.x; h[73] = (double)xa.y; h[74] = (double)xa.z; h[75] = (double)xa.w;
    h[76] = (double)xb.x; h[77] = (double)xb.y; h[78] = (double)xb.z; h[79] = (double)xb.w;

    layer_step<IN0 + 0 * NOPS, 72>(Wd + WOFF[0], h, hl, tid);  // in 8,  out@63 (regs)
    layer_step<IN0 + 1 * NOPS, 63>(Wd + WOFF[1], h, hl, tid);  // in 17, out@54 (regs)
    layer_step<IN0 + 2 * NOPS, 54>(Wd + WOFF[2], h, hl, tid);  // in 26, out@45 (regs)
    layer_step<IN0 + 3 * NOPS, 45>(Wd + WOFF[3], h, hl, tid);  // in 35, out@36 (regs)
    layer_step<IN0 + 4 * NOPS, 36>(Wd + WOFF[4], h, hl, tid);  // in 44, out@27 (regs)
    layer_step<IN0 + 5 * NOPS, 27>(Wd + WOFF[5], h, hl, tid);  // in 53, out@18 (18..25 LDS)
    layer_step<IN0 + 6 * NOPS, 18>(Wd + WOFF[6], h, hl, tid);  // in 62, out@9  (LDS)
    layer_step<IN0 + 7 * NOPS,  9>(Wd + WOFF[7], h, hl, tid);  // in 71, out@0  (LDS)

    // Final dot stays unrolled: indices must remain static (reg half) /
    // compile-time offsets (LDS half). Same ascending-k fma chain.
    const double* Wf = Wd + WOFF[8];
    double acc = 0.0;
    #pragma unroll
    for (int k = 0; k < FDIM; ++k) {
        acc = fma(Wf[k], h_rd(h, hl, tid, k), acc);
    }
    out[row] = (float)acc;
}

extern "C" void kernel_launch(void* const* d_in, const int* in_sizes, int n_in,
                              void* d_out, int out_size, void* d_ws, size_t ws_size,
                              hipStream_t stream) {
    const float* x = (const float*)d_in[0];
    double* Wd     = (double*)d_ws;   // 4188 doubles = 33.5 KB
    float* out     = (float*)d_out;

    // widen weights (d_ws is re-poisoned before every call -> must rewrite)
    {
        dim3 grid((923 + 255) / 256, 9);
        widen_kernel<<<grid, 256, 0, stream>>>(
            (const float*)d_in[1], (const float*)d_in[2], (const float*)d_in[3],
            (const float*)d_in[4], (const float*)d_in[5], (const float*)d_in[6],
            (const float*)d_in[7], (const float*)d_in[8], (const float*)d_in[9],
            Wd);
    }

    int nrows = in_sizes[0] / IN0;
    int block = BDIM;
    int grid  = (nrows + block - 1) / block;
    net_kernel<<<grid, block, 0, stream>>>(x, Wd, out, nrows);
}

// Round 2
// 306.214 us; speedup vs baseline: 2.1546x; 2.1546x over previous
//
#include <hip/hip_runtime.h>
#include <math.h>

// NetNew_17162689315115: 8-layer EQL-style net, B=524288 rows.
// Reference is numpy float64; chaotic map (sin/cos at |z|~1e8-1e14) -> ENTIRE
// chain in fp64, bitwise-frozen since R3 (absmax 1245184 / thr 1646264).
// DO NOT reassociate: each z[j] = fma(W[j,k], h[k], acc) ascending k.
//
// Evidence log:
//  R4 407us (fp64 weights pre-widened to d_ws). R5/R6 allocator hints:
//  regress badly — do not reintroduce. R7 block 64 vs 256: neutral.
//  R8 j-blocking: exactly neutral -> "spills" are AGPR moves (unified file:
//  ~112 arch VGPR + ~112 AGPR = 224 total -> 2 waves/SIMD hard cap; explains
//  occupancy 22.5% at all VGPR counts and zero scratch HBM traffic).
//  R9 I$ shrink (rolled j-loop + shared noinline transcendentals):
//  407 -> 222us, busy-time 265 -> 127us. I$ thrash confirmed.
//  R10 merged 4 transcendentals into one call: ~neutral — ocml sin/cos are
//  branchy (PH slow path), scheduler can't interleave across control flow.
//  R11 inline exp/log, shared noinline sincos: 222 -> 214us (VALUBusy 56%,
//  occupancy 22.7% == 2 waves/SIMD, HBM 0.6% — latency-bound on wave count).
//  R12 LDS h-split + __launch_bounds__(64,3): 214 -> 604us REGRESSION.
//  Occupancy did rise (31%) but WRITE_SIZE 2MB->90MB = ~21 doubles/thread
//  scratch spill; the 3-wave corridor (85 reg-doubles + 26 LDS-doubles = 111)
//  cannot hold the true live set (~118+ doubles). 2 waves/SIMD is the
//  structural occupancy ceiling — DO NOT revisit the occupancy axis.
// R13: attack the 44% idle at fixed occupancy. Busy floor ~= 120us of 213.
// Matmul-section busy model: 2 chains (unroll 2) x 2 waves x 4cyc issue /
// ~16cyc fp64-fma dep latency = 50% ~= measured 56%. Widen j-unroll to 4:
// 4 indep chains x 2 waves x 4 = 16/16 -> ~full issue in matmul sections.
// Accumulators ARE z[j] (already live) -> ~zero extra registers, no tier
// risk. Bitwise-neutral: each z[j] chain unchanged, ascending k.

static constexpr double MAX_MLT   = 99999999.0;
static constexpr double MAX_DIV   = 9999.0;
static constexpr double MAX_EXP_C = 17.0;
static constexpr double MIN_DENOM = 0.0001;

static constexpr int IN0  = 8;   // vari_num + const_num
static constexpr int VDIM = 13;  // rows of each W
static constexpr int NOPS = 9;   // ops appended per layer
static constexpr int FDIM = 80;  // final h dim: 8 + 8*9

// layer weight element counts and fp64 workspace offsets
// in_dims: 8,17,26,35,44,53,62,71 ; W_i is 13 x in_dim ; Wf is 1 x 80
static constexpr int WSZ[9]  = {104, 221, 338, 455, 572, 689, 806, 923, 80};
static constexpr int WOFF[9] = {0, 104, 325, 663, 1118, 1690, 2379, 3185, 4108};

// ---- prep: widen fp32 weights -> fp64 workspace (exact, bitwise-neutral) ----
__global__ void widen_kernel(const float* __restrict__ s0, const float* __restrict__ s1,
                             const float* __restrict__ s2, const float* __restrict__ s3,
                             const float* __restrict__ s4, const float* __restrict__ s5,
                             const float* __restrict__ s6, const float* __restrict__ s7,
                             const float* __restrict__ s8, double* __restrict__ dst) {
    int seg = blockIdx.y;
    int i   = blockIdx.x * blockDim.x + threadIdx.x;
    const float* src;
    switch (seg) {
        case 0: src = s0; break; case 1: src = s1; break; case 2: src = s2; break;
        case 3: src = s3; break; case 4: src = s4; break; case 5: src = s5; break;
        case 6: src = s6; break; case 7: src = s7; break; default: src = s8; break;
    }
    if (i < WSZ[seg]) dst[WOFF[seg] + i] = (double)src[i];
}

// ---- one shared body for the two PH-heavy (branchy) functions ----
struct D2 { double s, c; };
__device__ __attribute__((noinline))
D2 d_sincos2(double as, double ac) {
    D2 r;
    r.s = sin(as);
    r.c = cos(ac);
    return r;
}

// _clip_mag forward, float64: scale = |mx/v|, o = where(|v|>=mx, v*scale, v).
// NaN passes through (compare false), matching jnp.where.
__device__ __forceinline__ double clip_ref(double v, double mx) {
    double scale = fabs(mx / v);
    double vs    = v * scale;
    return (fabs(v) >= mx) ? vs : v;
}

template<int IN_DIM, int BASE>
__device__ __forceinline__ void layer_step(const double* __restrict__ W,
                                           double (&h)[FDIM]) {
    double z[VDIM];
    // Rolled j-loop, unroll 4: four INDEPENDENT fma chains in flight per wave
    // (2 waves/SIMD x 4 chains x 4cyc issue covers ~16cyc fp64 dep latency).
    // Each z[j] is the same ascending-k fma chain as the fully-unrolled form
    // -> bitwise equal. k stays unrolled so every h index is compile-time
    // constant (register/AGPR-resident).
    #pragma unroll 4
    for (int j = 0; j < VDIM; ++j) {
        const double* Wr = W + j * IN_DIM;
        double acc = 0.0;
        #pragma unroll
        for (int k = 0; k < IN_DIM; ++k) {
            acc = fma(Wr[k], h[BASE + k], acc);  // frozen accum order
        }
        z[j] = acc;
    }
    constexpr int BO = BASE - NOPS;
    // op order: + - * / sin cos exp log square, consuming z cols in order
    h[BO + 0] = z[0] + z[1];
    h[BO + 1] = z[2] - z[3];
    h[BO + 2] = clip_ref(z[4] * z[5], MAX_MLT);
    {
        double b     = z[7];
        double denom = (b == 0.0) ? (b + MIN_DENOM) : b;
        h[BO + 3]    = clip_ref(z[6] / denom, MAX_DIV);
    }
    {
        D2 t = d_sincos2(z[8], z[9]);   // shared noinline: PH-heavy bodies
        h[BO + 4] = t.s;
        h[BO + 5] = t.c;
    }
    {
        double a    = z[10];
        double safe = (a >= MAX_EXP_C) ? (a * (MAX_EXP_C / a)) : a;
        h[BO + 6]   = exp(safe);        // inlined: branch-light, schedules in
    }
    h[BO + 7] = log(fabs(z[11]));       // inlined: branch-light
    h[BO + 8] = clip_ref(z[12] * z[12], MAX_MLT);
}

__global__ void __launch_bounds__(64)
net_kernel(const float* __restrict__ x, const double* __restrict__ Wd,
           float* __restrict__ out, int nrows) {
    int row = blockIdx.x * blockDim.x + threadIdx.x;
    if (row >= nrows) return;

    double h[FDIM];

    // x occupies the TAIL of the final feature vector (each layer prepends).
    const float4* x4 = reinterpret_cast<const float4*>(x);
    float4 xa = x4[row * 2 + 0];
    float4 xb = x4[row * 2 + 1];
    h[72] = (double)xa.x; h[73] = (double)xa.y; h[74] = (double)xa.z; h[75] = (double)xa.w;
    h[76] = (double)xb.x; h[77] = (double)xb.y; h[78] = (double)xb.z; h[79] = (double)xb.w;

    layer_step<IN0 + 0 * NOPS, 72>(Wd + WOFF[0], h);  // in_dim  8, write at 63
    layer_step<IN0 + 1 * NOPS, 63>(Wd + WOFF[1], h);  // in_dim 17, write at 54
    layer_step<IN0 + 2 * NOPS, 54>(Wd + WOFF[2], h);  // in_dim 26, write at 45
    layer_step<IN0 + 3 * NOPS, 45>(Wd + WOFF[3], h);  // in_dim 35, write at 36
    layer_step<IN0 + 4 * NOPS, 36>(Wd + WOFF[4], h);  // in_dim 44, write at 27
    layer_step<IN0 + 5 * NOPS, 27>(Wd + WOFF[5], h);  // in_dim 53, write at 18
    layer_step<IN0 + 6 * NOPS, 18>(Wd + WOFF[6], h);  // in_dim 62, write at  9
    layer_step<IN0 + 7 * NOPS,  9>(Wd + WOFF[7], h);  // in_dim 71, write at  0

    // Final dot stays unrolled: h indices must remain static (any dynamic h
    // access would force the whole array to scratch).
    const double* Wf = Wd + WOFF[8];
    double acc = 0.0;
    #pragma unroll
    for (int k = 0; k < FDIM; ++k) {
        acc = fma(Wf[k], h[k], acc);
    }
    out[row] = (float)acc;
}

extern "C" void kernel_launch(void* const* d_in, const int* in_sizes, int n_in,
                              void* d_out, int out_size, void* d_ws, size_t ws_size,
                              hipStream_t stream) {
    const float* x = (const float*)d_in[0];
    double* Wd     = (double*)d_ws;   // 4188 doubles = 33.5 KB
    float* out     = (float*)d_out;

    // widen weights (d_ws is re-poisoned before every call -> must rewrite)
    {
        dim3 grid((923 + 255) / 256, 9);
        widen_kernel<<<grid, 256, 0, stream>>>(
            (const float*)d_in[1], (const float*)d_in[2], (const float*)d_in[3],
            (const float*)d_in[4], (const float*)d_in[5], (const float*)d_in[6],
            (const float*)d_in[7], (const float*)d_in[8], (const float*)d_in[9],
            Wd);
    }

    int nrows = in_sizes[0] / IN0;
    int block = 64;
    int grid  = (nrows + block - 1) / block;
    net_kernel<<<grid, block, 0, stream>>>(x, Wd, out, nrows);
}